// Round 4
// baseline (588.397 us; speedup 1.0000x reference)
//
#include <hip/hip_runtime.h>
#include <stdint.h>

typedef unsigned short ushortT;
typedef __attribute__((ext_vector_type(8))) short short8;
typedef __attribute__((ext_vector_type(4))) float float4_;

#define HH 4
#define FF 32
#define HFD 128
#define F_IN 128
#define EDGE_DIM 64
#define HIDDEN 256
#define BB 64
#define MLE 1500
#define NN 96000
#define EEc 600000
#define CAP 32

__device__ __forceinline__ float bf_lo(uint32_t u){ return __uint_as_float(u << 16); }
__device__ __forceinline__ float bf_hi(uint32_t u){ return __uint_as_float(u & 0xffff0000u); }
__device__ __forceinline__ uint32_t f2bf(float f){
    uint32_t u = __float_as_uint(f);
    return (u + 0x7fffu + ((u >> 16) & 1u)) >> 16;
}
__device__ __forceinline__ short8 cvt8(const float* p){
    float4_ x0 = *(const float4_*)p;
    float4_ x1 = *(const float4_*)(p + 4);
    short8 r;
    r[0]=(short)f2bf(x0[0]); r[1]=(short)f2bf(x0[1]); r[2]=(short)f2bf(x0[2]); r[3]=(short)f2bf(x0[3]);
    r[4]=(short)f2bf(x1[0]); r[5]=(short)f2bf(x1[1]); r[6]=(short)f2bf(x1[2]); r[7]=(short)f2bf(x1[3]);
    return r;
}

// ---------------------------------------------------------------------------
// K1: bridges (fp32).  csrc[b,hf]=(ins@Wsrc+bsrc)*a_src ; ctrg likewise.
//     cedge in LDS, then M2[b][h][d] = sum_f W_edge[d,h*32+f] * cedge[b,h*32+f]
//     M layout [b][h][d] so k_score group-loads contiguous 256B runs.
// grid: 64 blocks x 128 threads
// ---------------------------------------------------------------------------
__global__ void k_bridge(const float* ins, const float* Wsrc, const float* bsrc,
                         const float* Wtrg, const float* btrg,
                         const float* Wedg, const float* bedg,
                         const float* a_src, const float* a_trg, const float* a_edge,
                         const float* W_edge,
                         float* csrc, float* ctrg, float* Mout)
{
    __shared__ float ins_s[HIDDEN];
    __shared__ float ce_s[HFD];
    int b = blockIdx.x, t = threadIdx.x;  // t in [0,128)
    const float* ip = ins + b * HIDDEN;
    ins_s[t]       = ip[t];
    ins_s[t + 128] = ip[t + 128];
    __syncthreads();
    float as = 0.f, at = 0.f, ae = 0.f;
    #pragma unroll 8
    for (int k = 0; k < HIDDEN; k++){
        float iv = ins_s[k];
        as += iv * Wsrc[k*HFD + t];
        at += iv * Wtrg[k*HFD + t];
        ae += iv * Wedg[k*HFD + t];
    }
    csrc[b*HFD + t] = (as + bsrc[t]) * a_src[t];
    ctrg[b*HFD + t] = (at + btrg[t]) * a_trg[t];
    ce_s[t] = (ae + bedg[t]) * a_edge[t];
    __syncthreads();
    #pragma unroll
    for (int rep = 0; rep < 2; rep++){
        int idx = t + rep * 128;      // 0..255
        int d = idx >> 2, h = idx & 3;
        float acc = 0.f;
        #pragma unroll
        for (int f = 0; f < FF; f++)
            acc += W_edge[d*HFD + h*FF + f] * ce_s[h*FF + f];
        Mout[b*256 + h*64 + d] = acc;       // transposed: [b][h][d]
    }
}

// ---------------------------------------------------------------------------
// K_t: WcatT[c][d] = bf16( c<128 ? W_proj[d][c] : W_skip[d][c-128] )
// grid: 128 blocks x 256 threads
// ---------------------------------------------------------------------------
__global__ void k_transpose(const float* Wp, const float* Wsk, ushortT* WcatT)
{
    int idx = blockIdx.x * 256 + threadIdx.x;
    int c = idx >> 7;          // 0..255
    int d = idx & 127;         // 0..127
    float v = (c < 128) ? Wp[d*128 + c] : Wsk[d*128 + (c - 128)];
    WcatT[c*128 + d] = (ushortT)f2bf(v);
}

// ---------------------------------------------------------------------------
// K2: GEMM + fused scores (unchanged).
// grid: 1500 blocks x 256 threads
// ---------------------------------------------------------------------------
__global__ __launch_bounds__(256) void k_gemm(const float* x, const ushortT* WcatT,
                                              const float* csrc, const float* ctrg,
                                              ushortT* proj, ushortT* skip,
                                              float* s_src, float* s_trg)
{
    int t = threadIdx.x;
    int w = t >> 6, lane = t & 63;
    int q = lane >> 4, n16 = lane & 15;
    size_t node = (size_t)blockIdx.x * 64 + w * 16 + n16;

    float4_ acc[16];
    #pragma unroll
    for (int j = 0; j < 16; j++) acc[j] = (float4_){0.f, 0.f, 0.f, 0.f};

    #pragma unroll
    for (int kk = 0; kk < 4; kk++){
        short8 bfrag = cvt8(x + node * 128 + kk*32 + q*8);   // B[k][n=node]
        #pragma unroll
        for (int j = 0; j < 16; j++){
            short8 afrag = *(const short8*)(WcatT + (size_t)(j*16 + n16) * 128 + kk*32 + q*8);
            acc[j] = __builtin_amdgcn_mfma_f32_16x16x32_bf16(afrag, bfrag, acc[j], 0, 0, 0);
        }
    }

    // ---- store proj (j<8) / skip (j>=8): 8B packed per j ----
    #pragma unroll
    for (int j = 0; j < 16; j++){
        uint32_t p0 = f2bf(acc[j][0]) | (f2bf(acc[j][1]) << 16);
        uint32_t p1 = f2bf(acc[j][2]) | (f2bf(acc[j][3]) << 16);
        ushortT* base = (j < 8) ? (proj + node*128 + j*16 + q*4)
                                : (skip + node*128 + (j-8)*16 + q*4);
        uint2 pv; pv.x = p0; pv.y = p1;
        *(uint2*)base = pv;
    }

    // ---- fused scores: s[n,h] = sum_f proj_f32[n,h*32+f] * c[b,h*32+f] ----
    int b = (int)(node / MLE);
    const float* cs = csrc + b * HFD;
    const float* ct = ctrg + b * HFD;
    float ps[4] = {0,0,0,0}, pt[4] = {0,0,0,0};
    #pragma unroll
    for (int j = 0; j < 8; j++){
        int h = j >> 1;
        #pragma unroll
        for (int r = 0; r < 4; r++){
            int c = j*16 + q*4 + r;
            ps[h] += acc[j][r] * cs[c];
            pt[h] += acc[j][r] * ct[c];
        }
    }
    #pragma unroll
    for (int m = 16; m < 64; m <<= 1){
        #pragma unroll
        for (int hh = 0; hh < 4; hh++){
            ps[hh] += __shfl_xor(ps[hh], m, 64);
            pt[hh] += __shfl_xor(pt[hh], m, 64);
        }
    }
    float vs = (q == 0) ? ps[0] : (q == 1) ? ps[1] : (q == 2) ? ps[2] : ps[3];
    float vt = (q == 0) ? pt[0] : (q == 1) ? pt[1] : (q == 2) ? pt[2] : pt[3];
    s_src[node*4 + q] = vs;
    s_trg[node*4 + q] = vt;
}

// ---------------------------------------------------------------------------
// K4a (k_score): streaming per-edge scores + exp -> coalesced REC stream.
//   NO atomics, NO scattered stores.  Cooperative 16-edges-per-wave layout.
//   eidx -> s gather chain hoisted to the top so it overlaps the M-dot work.
//   REC[e] = {src, trg, bf16(ex0)|bf16(ex1), bf16(ex2)|bf16(ex3)}  (16B)
// grid: E/64 blocks x 256 threads
// ---------------------------------------------------------------------------
__global__ __launch_bounds__(256) void k_score(const int* eidx, const int* bids,
    const float* edges, const float* M, const float* s_src, const float* s_trg,
    uint4* recs)
{
    int t = threadIdx.x;
    int wave = t >> 6, l = t & 63;
    int g = l >> 4, s = l & 15;
    int eb = (blockIdx.x * 4 + wave) * 16;   // first edge of this wave's tile

    // ---- hoisted: per-lane epilogue edge + dependent s-gather chain
    int i_sel = s >> 2;
    int h_sel = s & 3;
    int e   = eb + i_sel*4 + g;
    int src = eidx[e];
    int trg = eidx[EEc + e];
    float ssv = s_src[(size_t)src*4 + h_sel];
    float stv = s_trg[(size_t)trg*4 + h_sel];

    // ---- coalesced edge-row loads: lane holds floats d=s*4..s*4+3 of row i*4+g
    float4_ ev[4];
    int bidv[4];
    #pragma unroll
    for (int i = 0; i < 4; i++){
        int r = i*4 + g;
        ev[i]   = *(const float4_*)(edges + (size_t)(eb + r) * 64 + s*4);
        bidv[i] = bids[eb + r];
    }

    // ---- partial dots against M2[bid][h][d] (group-uniform bid -> contiguous)
    float p00=0.f,p01=0.f,p02=0.f,p03=0.f;
    float p10=0.f,p11=0.f,p12=0.f,p13=0.f;
    float p20=0.f,p21=0.f,p22=0.f,p23=0.f;
    float p30=0.f,p31=0.f,p32=0.f,p33=0.f;
    #pragma unroll
    for (int i = 0; i < 4; i++){
        const float* Mb = M + (size_t)bidv[i] * 256;
        float4_ m0 = *(const float4_*)(Mb +   0 + s*4);
        float4_ m1 = *(const float4_*)(Mb +  64 + s*4);
        float4_ m2 = *(const float4_*)(Mb + 128 + s*4);
        float4_ m3 = *(const float4_*)(Mb + 192 + s*4);
        float4_ e4 = ev[i];
        float d0 = e4[0]*m0[0] + e4[1]*m0[1] + e4[2]*m0[2] + e4[3]*m0[3];
        float d1 = e4[0]*m1[0] + e4[1]*m1[1] + e4[2]*m1[2] + e4[3]*m1[3];
        float d2 = e4[0]*m2[0] + e4[1]*m2[1] + e4[2]*m2[2] + e4[3]*m2[3];
        float d3 = e4[0]*m3[0] + e4[1]*m3[1] + e4[2]*m3[2] + e4[3]*m3[3];
        if (i == 0){ p00=d0; p01=d1; p02=d2; p03=d3; }
        if (i == 1){ p10=d0; p11=d1; p12=d2; p13=d3; }
        if (i == 2){ p20=d0; p21=d1; p22=d2; p23=d3; }
        if (i == 3){ p30=d0; p31=d1; p32=d2; p33=d3; }
    }

    // ---- reduce over the 16-lane group (xor 1,2,4,8 stays within group)
    #pragma unroll
    for (int mm = 1; mm < 16; mm <<= 1){
        p00 += __shfl_xor(p00, mm, 64); p01 += __shfl_xor(p01, mm, 64);
        p02 += __shfl_xor(p02, mm, 64); p03 += __shfl_xor(p03, mm, 64);
        p10 += __shfl_xor(p10, mm, 64); p11 += __shfl_xor(p11, mm, 64);
        p12 += __shfl_xor(p12, mm, 64); p13 += __shfl_xor(p13, mm, 64);
        p20 += __shfl_xor(p20, mm, 64); p21 += __shfl_xor(p21, mm, 64);
        p22 += __shfl_xor(p22, mm, 64); p23 += __shfl_xor(p23, mm, 64);
        p30 += __shfl_xor(p30, mm, 64); p31 += __shfl_xor(p31, mm, 64);
        p32 += __shfl_xor(p32, mm, 64); p33 += __shfl_xor(p33, mm, 64);
    }

    // ---- epilogue: lane (g, s) handles edge eb + (s>>2)*4 + g, head s&3
    float q0 = h_sel==0 ? p00 : h_sel==1 ? p01 : h_sel==2 ? p02 : p03;
    float q1 = h_sel==0 ? p10 : h_sel==1 ? p11 : h_sel==2 ? p12 : p13;
    float q2 = h_sel==0 ? p20 : h_sel==1 ? p21 : h_sel==2 ? p22 : p23;
    float q3 = h_sel==0 ? p30 : h_sel==1 ? p31 : h_sel==2 ? p32 : p33;
    float se = i_sel==0 ? q0 : i_sel==1 ? q1 : i_sel==2 ? q2 : q3;

    float sc = ssv + stv + se;
    sc = sc > 0.f ? sc : 0.2f * sc;
    float exv = __expf(sc);

    // pack the cluster's 4 head values as bf16x4 into lane h_sel==0
    uint32_t my   = f2bf(exv) << ((h_sel & 1) * 16);
    uint32_t pair = my | __shfl_xor(my, 1, 64);       // h0: ex0|ex1  h2: ex2|ex3
    uint32_t both = __shfl_xor(pair, 2, 64);          // h0: ex2|ex3

    if (h_sel == 0){
        uint4 rec;
        rec.x = (uint32_t)src; rec.y = (uint32_t)trg;
        rec.z = pair; rec.w = both;
        recs[e] = rec;                                 // coalesced 16B stream
    }
}

// ---------------------------------------------------------------------------
// K4b (k_build): adjacency lists only.  One edge per lane, all 64 lanes do
//   atomics -> 4x the atomic parallelism of the fused epilogue, full 32-wave
//   occupancy (no LDS, tiny VGPR), nothing else on the critical path.
// grid: ceil(E/256) x 256
// ---------------------------------------------------------------------------
__global__ __launch_bounds__(256) void k_build(const int* eidx,
    int* cnt_src, int* cnt_trg, uint32_t* adj_src, uint32_t* adj_trg)
{
    int e = blockIdx.x * 256 + threadIdx.x;
    if (e >= EEc) return;
    int src = eidx[e];
    int trg = eidx[EEc + e];
    int sl = atomicAdd(&cnt_src[src], 1);
    if (sl < CAP) adj_src[(size_t)src*CAP + sl] = (uint32_t)e;
    int sl2 = atomicAdd(&cnt_trg[trg], 1);
    if (sl2 < CAP) adj_trg[(size_t)trg*CAP + sl2] = (uint32_t)e;
}

// ---------------------------------------------------------------------------
// K5: fused aggregation + softmax + skip + bias + LayerNorm (unchanged).
// grid: 24000 blocks x 256 threads (one wave per node)
// ---------------------------------------------------------------------------
__global__ __launch_bounds__(256) void k_agg(const ushortT* proj, const ushortT* skip,
    const float* bias,
    const int* cnt_src, const int* cnt_trg,
    const uint32_t* adj_src, const uint32_t* adj_trg, const uint4* recs,
    const float* gamma, const float* beta, float* out)
{
    __shared__ int   sh_nbr[2][4][CAP];
    __shared__ float sh_ev [2][4][CAP*4];

    int wave = threadIdx.x >> 6, lane = threadIdx.x & 63;
    int n = blockIdx.x * 4 + wave;
    int h = lane >> 4;

    int cnt0 = cnt_src[n]; if (cnt0 > CAP) cnt0 = CAP;
    int cnt1 = cnt_trg[n]; if (cnt1 > CAP) cnt1 = CAP;

    // phase 1: ref -> REC (both direction refs issued first for MLP)
    uint32_t e0 = 0, e1 = 0;
    if (lane < cnt0) e0 = adj_src[(size_t)n * CAP + lane];
    if (lane < cnt1) e1 = adj_trg[(size_t)n * CAP + lane];
    if (lane < cnt0){
        uint4 rec = recs[e0];
        sh_nbr[0][wave][lane] = (int)rec.y;            // trg endpoint
        float4_ evv = { bf_lo(rec.z), bf_hi(rec.z), bf_lo(rec.w), bf_hi(rec.w) };
        *(float4_*)&sh_ev[0][wave][lane*4] = evv;
    }
    if (lane < cnt1){
        uint4 rec = recs[e1];
        sh_nbr[1][wave][lane] = (int)rec.x;            // src endpoint
        float4_ evv = { bf_lo(rec.z), bf_hi(rec.z), bf_lo(rec.w), bf_hi(rec.w) };
        *(float4_*)&sh_ev[1][wave][lane*4] = evv;
    }

    // skip + bias (issued before the barrier to overlap)
    uint32_t sv = ((const uint32_t*)(skip + (size_t)n * 128))[lane];
    float b0 = bias[2*lane], b1 = bias[2*lane + 1];

    __syncthreads();

    float sk0 = bf_lo(sv) + b0;
    float sk1 = bf_hi(sv) + b1;

    // phase 2a: src-direction aggregation (cols 0..127)
    float a0 = 0.f, a1 = 0.f, ad = 0.f;
    #pragma unroll 4
    for (int i = 0; i < cnt0; i++){
        int nbr  = sh_nbr[0][wave][i];
        float evw = sh_ev[0][wave][i*4 + h];
        uint32_t pv = ((const uint32_t*)(proj + (size_t)nbr * 128))[lane];
        a0 += evw * bf_lo(pv);
        a1 += evw * bf_hi(pv);
        ad += evw;
    }
    float inv = 1.f / (ad + 1e-16f);
    float f0 = a0 * inv + sk0;
    float f1 = a1 * inv + sk1;

    // phase 2b: trg-direction aggregation (cols 128..255)
    a0 = 0.f; a1 = 0.f; ad = 0.f;
    #pragma unroll 4
    for (int i = 0; i < cnt1; i++){
        int nbr  = sh_nbr[1][wave][i];
        float evw = sh_ev[1][wave][i*4 + h];
        uint32_t pv = ((const uint32_t*)(proj + (size_t)nbr * 128))[lane];
        a0 += evw * bf_lo(pv);
        a1 += evw * bf_hi(pv);
        ad += evw;
    }
    inv = 1.f / (ad + 1e-16f);
    float f2 = a0 * inv + sk0;
    float f3 = a1 * inv + sk1;

    // LayerNorm over 256 features
    float sum = f0 + f1 + f2 + f3;
    float sq  = f0*f0 + f1*f1 + f2*f2 + f3*f3;
    #pragma unroll
    for (int m = 1; m < 64; m <<= 1){
        sum += __shfl_xor(sum, m, 64);
        sq  += __shfl_xor(sq,  m, 64);
    }
    float mu  = sum * (1.f/256.f);
    float var = sq * (1.f/256.f) - mu*mu;
    var = var < 0.f ? 0.f : var;
    float rr = rsqrtf(var + 1e-5f);

    float o0 = (f0 - mu) * rr * gamma[2*lane]           + beta[2*lane];
    float o1 = (f1 - mu) * rr * gamma[2*lane + 1]       + beta[2*lane + 1];
    float o2 = (f2 - mu) * rr * gamma[128 + 2*lane]     + beta[128 + 2*lane];
    float o3 = (f3 - mu) * rr * gamma[128 + 2*lane + 1] + beta[128 + 2*lane + 1];

    float* orow = out + (size_t)n * 256;
    *(float2*)(orow + 2*lane)       = make_float2(o0, o1);
    *(float2*)(orow + 128 + 2*lane) = make_float2(o2, o3);
}

// ---------------------------------------------------------------------------
extern "C" void kernel_launch(void* const* d_in, const int* in_sizes, int n_in,
                              void* d_out, int out_size, void* d_ws, size_t ws_size,
                              hipStream_t stream)
{
    const float* x      = (const float*)d_in[0];
    const int*   eidx   = (const int*)d_in[1];
    const float* edges  = (const float*)d_in[2];
    const float* ins    = (const float*)d_in[3];
    const int*   bids   = (const int*)d_in[4];
    const float* Wproj  = (const float*)d_in[6];
    const float* Wedge  = (const float*)d_in[7];
    const float* Wsrc   = (const float*)d_in[8];
    const float* bsrc   = (const float*)d_in[9];
    const float* Wtrg   = (const float*)d_in[10];
    const float* btrg   = (const float*)d_in[11];
    const float* Wedgi  = (const float*)d_in[12];
    const float* bedgi  = (const float*)d_in[13];
    const float* a_src  = (const float*)d_in[14];
    const float* a_trg  = (const float*)d_in[15];
    const float* a_edge = (const float*)d_in[16];
    const float* bias   = (const float*)d_in[17];
    const float* Wskip  = (const float*)d_in[18];
    const float* gamma  = (const float*)d_in[19];
    const float* beta   = (const float*)d_in[20];

    char* ws = (char*)d_ws;
    size_t off = 0;
    ushortT* proj  = (ushortT*)(ws + off); off += (size_t)NN * 128 * 2;
    ushortT* skip  = (ushortT*)(ws + off); off += (size_t)NN * 128 * 2;
    ushortT* WcatT = (ushortT*)(ws + off); off += 256 * 128 * 2;
    float*   csrc  = (float*)(ws + off);   off += BB * HFD * 4;
    float*   ctrg  = (float*)(ws + off);   off += BB * HFD * 4;
    float*   M     = (float*)(ws + off);   off += BB * 256 * 4;
    float*   s_src = (float*)(ws + off);   off += (size_t)NN * 4 * 4;
    float*   s_trg = (float*)(ws + off);   off += (size_t)NN * 4 * 4;
    int*     cnt_src = (int*)(ws + off);   off += (size_t)NN * 4;
    int*     cnt_trg = (int*)(ws + off);   off += (size_t)NN * 4;
    uint32_t* adj_src = (uint32_t*)(ws + off); off += (size_t)NN * CAP * 4;
    uint32_t* adj_trg = (uint32_t*)(ws + off); off += (size_t)NN * CAP * 4;
    uint4*   recs  = (uint4*)(ws + off);   off += (size_t)EEc * 16;

    hipMemsetAsync(cnt_src, 0, (size_t)NN * 4 * 2, stream);  // cnt_src+cnt_trg contiguous

    k_bridge<<<dim3(BB), dim3(128), 0, stream>>>(ins, Wsrc, bsrc, Wtrg, btrg, Wedgi, bedgi,
                                                 a_src, a_trg, a_edge, Wedge, csrc, ctrg, M);
    k_transpose<<<dim3(128), dim3(256), 0, stream>>>(Wproj, Wskip, WcatT);
    k_build<<<dim3((EEc + 255)/256), dim3(256), 0, stream>>>(eidx, cnt_src, cnt_trg,
                                                             adj_src, adj_trg);
    k_gemm<<<dim3(NN/64), dim3(256), 0, stream>>>(x, WcatT, csrc, ctrg, proj, skip, s_src, s_trg);
    k_score<<<dim3(EEc/64), dim3(256), 0, stream>>>(eidx, bids, edges, M, s_src, s_trg, recs);
    k_agg<<<dim3(NN/4), dim3(256), 0, stream>>>(proj, skip, bias, cnt_src, cnt_trg,
                                                adj_src, adj_trg, recs, gamma, beta, (float*)d_out);
}

// Round 6
// 540.386 us; speedup vs baseline: 1.0888x; 1.0888x over previous
//
#include <hip/hip_runtime.h>
#include <stdint.h>

typedef unsigned short ushortT;
typedef __attribute__((ext_vector_type(8))) short short8;
typedef __attribute__((ext_vector_type(4))) float float4_;

#define HH 4
#define FF 32
#define HFD 128
#define F_IN 128
#define EDGE_DIM 64
#define HIDDEN 256
#define BB 64
#define MLE 1500
#define NN 96000
#define EEc 600000
#define CAP 32

__device__ __forceinline__ float bf_lo(uint32_t u){ return __uint_as_float(u << 16); }
__device__ __forceinline__ float bf_hi(uint32_t u){ return __uint_as_float(u & 0xffff0000u); }
__device__ __forceinline__ uint32_t f2bf(float f){
    uint32_t u = __float_as_uint(f);
    return (u + 0x7fffu + ((u >> 16) & 1u)) >> 16;
}
__device__ __forceinline__ short8 cvt8(const float* p){
    float4_ x0 = *(const float4_*)p;
    float4_ x1 = *(const float4_*)(p + 4);
    short8 r;
    r[0]=(short)f2bf(x0[0]); r[1]=(short)f2bf(x0[1]); r[2]=(short)f2bf(x0[2]); r[3]=(short)f2bf(x0[3]);
    r[4]=(short)f2bf(x1[0]); r[5]=(short)f2bf(x1[1]); r[6]=(short)f2bf(x1[2]); r[7]=(short)f2bf(x1[3]);
    return r;
}

// ---------------------------------------------------------------------------
// K1: bridges (fp32).  csrc[b,hf]=(ins@Wsrc+bsrc)*a_src ; ctrg likewise.
//     cedge in LDS, then M2[b][h][d] = sum_f W_edge[d,h*32+f] * cedge[b,h*32+f]
//     M layout [b][h][d] so k_score group-loads contiguous 256B runs.
// grid: 64 blocks x 128 threads
// ---------------------------------------------------------------------------
__global__ void k_bridge(const float* ins, const float* Wsrc, const float* bsrc,
                         const float* Wtrg, const float* btrg,
                         const float* Wedg, const float* bedg,
                         const float* a_src, const float* a_trg, const float* a_edge,
                         const float* W_edge,
                         float* csrc, float* ctrg, float* Mout)
{
    __shared__ float ins_s[HIDDEN];
    __shared__ float ce_s[HFD];
    int b = blockIdx.x, t = threadIdx.x;  // t in [0,128)
    const float* ip = ins + b * HIDDEN;
    ins_s[t]       = ip[t];
    ins_s[t + 128] = ip[t + 128];
    __syncthreads();
    float as = 0.f, at = 0.f, ae = 0.f;
    #pragma unroll 8
    for (int k = 0; k < HIDDEN; k++){
        float iv = ins_s[k];
        as += iv * Wsrc[k*HFD + t];
        at += iv * Wtrg[k*HFD + t];
        ae += iv * Wedg[k*HFD + t];
    }
    csrc[b*HFD + t] = (as + bsrc[t]) * a_src[t];
    ctrg[b*HFD + t] = (at + btrg[t]) * a_trg[t];
    ce_s[t] = (ae + bedg[t]) * a_edge[t];
    __syncthreads();
    #pragma unroll
    for (int rep = 0; rep < 2; rep++){
        int idx = t + rep * 128;      // 0..255
        int d = idx >> 2, h = idx & 3;
        float acc = 0.f;
        #pragma unroll
        for (int f = 0; f < FF; f++)
            acc += W_edge[d*HFD + h*FF + f] * ce_s[h*FF + f];
        Mout[b*256 + h*64 + d] = acc;       // transposed: [b][h][d]
    }
}

// ---------------------------------------------------------------------------
// K_t: WcatT[c][d] = bf16( c<128 ? W_proj[d][c] : W_skip[d][c-128] )
// grid: 128 blocks x 256 threads
// ---------------------------------------------------------------------------
__global__ void k_transpose(const float* Wp, const float* Wsk, ushortT* WcatT)
{
    int idx = blockIdx.x * 256 + threadIdx.x;
    int c = idx >> 7;          // 0..255
    int d = idx & 127;         // 0..127
    float v = (c < 128) ? Wp[d*128 + c] : Wsk[d*128 + (c - 128)];
    WcatT[c*128 + d] = (ushortT)f2bf(v);
}

// ---------------------------------------------------------------------------
// K2: GEMM + fused scores (unchanged).
// grid: 1500 blocks x 256 threads
// ---------------------------------------------------------------------------
__global__ __launch_bounds__(256) void k_gemm(const float* x, const ushortT* WcatT,
                                              const float* csrc, const float* ctrg,
                                              ushortT* proj, ushortT* skip,
                                              float* s_src, float* s_trg)
{
    int t = threadIdx.x;
    int w = t >> 6, lane = t & 63;
    int q = lane >> 4, n16 = lane & 15;
    size_t node = (size_t)blockIdx.x * 64 + w * 16 + n16;

    float4_ acc[16];
    #pragma unroll
    for (int j = 0; j < 16; j++) acc[j] = (float4_){0.f, 0.f, 0.f, 0.f};

    #pragma unroll
    for (int kk = 0; kk < 4; kk++){
        short8 bfrag = cvt8(x + node * 128 + kk*32 + q*8);   // B[k][n=node]
        #pragma unroll
        for (int j = 0; j < 16; j++){
            short8 afrag = *(const short8*)(WcatT + (size_t)(j*16 + n16) * 128 + kk*32 + q*8);
            acc[j] = __builtin_amdgcn_mfma_f32_16x16x32_bf16(afrag, bfrag, acc[j], 0, 0, 0);
        }
    }

    // ---- store proj (j<8) / skip (j>=8): 8B packed per j ----
    #pragma unroll
    for (int j = 0; j < 16; j++){
        uint32_t p0 = f2bf(acc[j][0]) | (f2bf(acc[j][1]) << 16);
        uint32_t p1 = f2bf(acc[j][2]) | (f2bf(acc[j][3]) << 16);
        ushortT* base = (j < 8) ? (proj + node*128 + j*16 + q*4)
                                : (skip + node*128 + (j-8)*16 + q*4);
        uint2 pv; pv.x = p0; pv.y = p1;
        *(uint2*)base = pv;
    }

    // ---- fused scores: s[n,h] = sum_f proj_f32[n,h*32+f] * c[b,h*32+f] ----
    int b = (int)(node / MLE);
    const float* cs = csrc + b * HFD;
    const float* ct = ctrg + b * HFD;
    float ps[4] = {0,0,0,0}, pt[4] = {0,0,0,0};
    #pragma unroll
    for (int j = 0; j < 8; j++){
        int h = j >> 1;
        #pragma unroll
        for (int r = 0; r < 4; r++){
            int c = j*16 + q*4 + r;
            ps[h] += acc[j][r] * cs[c];
            pt[h] += acc[j][r] * ct[c];
        }
    }
    #pragma unroll
    for (int m = 16; m < 64; m <<= 1){
        #pragma unroll
        for (int hh = 0; hh < 4; hh++){
            ps[hh] += __shfl_xor(ps[hh], m, 64);
            pt[hh] += __shfl_xor(pt[hh], m, 64);
        }
    }
    float vs = (q == 0) ? ps[0] : (q == 1) ? ps[1] : (q == 2) ? ps[2] : ps[3];
    float vt = (q == 0) ? pt[0] : (q == 1) ? pt[1] : (q == 2) ? pt[2] : pt[3];
    s_src[node*4 + q] = vs;
    s_trg[node*4 + q] = vt;
}

// ---------------------------------------------------------------------------
// K4 (k_score): streaming per-edge scores + exp -> coalesced REC stream,
//   PLUS linked-list adjacency build:
//     old = atomicExch(&head[node], e); next[e] = old;
//   The atomic hits a 375KB L2-hot array; the dependent store is indexed by
//   e (COALESCED).  No scattered 4B slot-stores, no line-granular writeback.
// grid: E/64 blocks x 256 threads (64 edges per block, 16 per wave)
// ---------------------------------------------------------------------------
__global__ __launch_bounds__(256) void k_score(const int* eidx, const int* bids,
    const float* edges, const float* M, const float* s_src, const float* s_trg,
    uint4* recs, int* head_src, int* head_trg, int* next_src, int* next_trg)
{
    int t = threadIdx.x;
    int wave = t >> 6, l = t & 63;
    int g = l >> 4, s = l & 15;
    int eb = (blockIdx.x * 4 + wave) * 16;   // first edge of this wave's tile

    // ---- hoisted: per-lane epilogue edge + dependent s-gather chain
    int i_sel = s >> 2;
    int h_sel = s & 3;
    int e   = eb + i_sel*4 + g;
    int src = eidx[e];
    int trg = eidx[EEc + e];
    float ssv = s_src[(size_t)src*4 + h_sel];
    float stv = s_trg[(size_t)trg*4 + h_sel];

    // ---- coalesced edge-row loads: lane holds floats d=s*4..s*4+3 of row i*4+g
    float4_ ev[4];
    int bidv[4];
    #pragma unroll
    for (int i = 0; i < 4; i++){
        int r = i*4 + g;
        ev[i]   = *(const float4_*)(edges + (size_t)(eb + r) * 64 + s*4);
        bidv[i] = bids[eb + r];
    }

    // ---- partial dots against M2[bid][h][d] (group-uniform bid -> contiguous)
    float p00=0.f,p01=0.f,p02=0.f,p03=0.f;
    float p10=0.f,p11=0.f,p12=0.f,p13=0.f;
    float p20=0.f,p21=0.f,p22=0.f,p23=0.f;
    float p30=0.f,p31=0.f,p32=0.f,p33=0.f;
    #pragma unroll
    for (int i = 0; i < 4; i++){
        const float* Mb = M + (size_t)bidv[i] * 256;
        float4_ m0 = *(const float4_*)(Mb +   0 + s*4);
        float4_ m1 = *(const float4_*)(Mb +  64 + s*4);
        float4_ m2 = *(const float4_*)(Mb + 128 + s*4);
        float4_ m3 = *(const float4_*)(Mb + 192 + s*4);
        float4_ e4 = ev[i];
        float d0 = e4[0]*m0[0] + e4[1]*m0[1] + e4[2]*m0[2] + e4[3]*m0[3];
        float d1 = e4[0]*m1[0] + e4[1]*m1[1] + e4[2]*m1[2] + e4[3]*m1[3];
        float d2 = e4[0]*m2[0] + e4[1]*m2[1] + e4[2]*m2[2] + e4[3]*m2[3];
        float d3 = e4[0]*m3[0] + e4[1]*m3[1] + e4[2]*m3[2] + e4[3]*m3[3];
        if (i == 0){ p00=d0; p01=d1; p02=d2; p03=d3; }
        if (i == 1){ p10=d0; p11=d1; p12=d2; p13=d3; }
        if (i == 2){ p20=d0; p21=d1; p22=d2; p23=d3; }
        if (i == 3){ p30=d0; p31=d1; p32=d2; p33=d3; }
    }

    // ---- reduce over the 16-lane group (xor 1,2,4,8 stays within group)
    #pragma unroll
    for (int mm = 1; mm < 16; mm <<= 1){
        p00 += __shfl_xor(p00, mm, 64); p01 += __shfl_xor(p01, mm, 64);
        p02 += __shfl_xor(p02, mm, 64); p03 += __shfl_xor(p03, mm, 64);
        p10 += __shfl_xor(p10, mm, 64); p11 += __shfl_xor(p11, mm, 64);
        p12 += __shfl_xor(p12, mm, 64); p13 += __shfl_xor(p13, mm, 64);
        p20 += __shfl_xor(p20, mm, 64); p21 += __shfl_xor(p21, mm, 64);
        p22 += __shfl_xor(p22, mm, 64); p23 += __shfl_xor(p23, mm, 64);
        p30 += __shfl_xor(p30, mm, 64); p31 += __shfl_xor(p31, mm, 64);
        p32 += __shfl_xor(p32, mm, 64); p33 += __shfl_xor(p33, mm, 64);
    }

    // ---- epilogue: lane (g, s) handles edge eb + (s>>2)*4 + g, head s&3
    float q0 = h_sel==0 ? p00 : h_sel==1 ? p01 : h_sel==2 ? p02 : p03;
    float q1 = h_sel==0 ? p10 : h_sel==1 ? p11 : h_sel==2 ? p12 : p13;
    float q2 = h_sel==0 ? p20 : h_sel==1 ? p21 : h_sel==2 ? p22 : p23;
    float q3 = h_sel==0 ? p30 : h_sel==1 ? p31 : h_sel==2 ? p32 : p33;
    float se = i_sel==0 ? q0 : i_sel==1 ? q1 : i_sel==2 ? q2 : q3;

    float sc = ssv + stv + se;
    sc = sc > 0.f ? sc : 0.2f * sc;
    float exv = __expf(sc);

    // pack the cluster's 4 head values as bf16x4 into lane h_sel==0
    uint32_t my   = f2bf(exv) << ((h_sel & 1) * 16);
    uint32_t pair = my | __shfl_xor(my, 1, 64);       // h0: ex0|ex1  h2: ex2|ex3
    uint32_t both = __shfl_xor(pair, 2, 64);          // h0: ex2|ex3

    if (h_sel == 0){
        uint4 rec;
        rec.x = (uint32_t)src; rec.y = (uint32_t)trg;
        rec.z = pair; rec.w = both;
        recs[e] = rec;                                 // coalesced 16B stream
        int old0 = atomicExch(&head_src[src], e);
        next_src[e] = old0;                            // coalesced 4B
        int old1 = atomicExch(&head_trg[trg], e);
        next_trg[e] = old1;                            // coalesced 4B
    }
}

// ---------------------------------------------------------------------------
// K4b (k_walk): linked lists -> transposed dense adjacency.
//   One node-direction per lane (192000 lanes = 750 blocks; all waves
//   co-resident -> the ~6-hop dependent-load chain is fully latency-hidden).
//   At hop c, all active lanes store at [c][n] with consecutive n: COALESCED.
//   Entry content (nbr + ex4) inlined from recs so k_agg needs no rec gather.
// grid: 750 blocks x 256 threads
// ---------------------------------------------------------------------------
__global__ __launch_bounds__(256) void k_walk(const int* head_src, const int* head_trg,
    const int* next_src, const int* next_trg, const uint4* recs,
    int* cnt_src, int* cnt_trg, uint32_t* nbrT, uint2* evT)   // [2][CAP][NN]
{
    int id = blockIdx.x * 256 + threadIdx.x;   // 0..191999, dir block-uniform
    int dir = (id >= NN) ? 1 : 0;
    int n = id - dir * NN;
    int e = dir ? head_trg[n] : head_src[n];
    const int* nx = dir ? next_trg : next_src;
    uint32_t* nT = nbrT + (size_t)dir * CAP * NN;
    uint2*    eT = evT  + (size_t)dir * CAP * NN;
    int c = 0;
    while (e >= 0 && c < CAP){
        uint4 r = recs[e];           // scattered 16B (L2/IC-hot, 9.6MB)
        int en = nx[e];              // independent of recs load
        nT[(size_t)c*NN + n] = dir ? r.x : r.y;
        eT[(size_t)c*NN + n] = make_uint2(r.z, r.w);
        e = en;
        c++;
    }
    if (dir) cnt_trg[n] = c; else cnt_src[n] = c;
}

// ---------------------------------------------------------------------------
// K5: fused aggregation + softmax + skip + bias + LayerNorm.
//     Phase 1 reads the transposed dense adjacency: nbrT/evT[l][n] lines are
//     shared by the block's 4 consecutive nodes (was: 2 random gathers/edge).
// grid: 24000 blocks x 256 threads (one wave per node)
// ---------------------------------------------------------------------------
__global__ __launch_bounds__(256) void k_agg(const ushortT* proj, const ushortT* skip,
    const float* bias,
    const int* cnt_src, const int* cnt_trg,
    const uint32_t* nbrT, const uint2* evT,
    const float* gamma, const float* beta, float* out)
{
    __shared__ int   sh_nbr[2][4][CAP];
    __shared__ float sh_ev [2][4][CAP*4];

    int wave = threadIdx.x >> 6, lane = threadIdx.x & 63;
    int n = blockIdx.x * 4 + wave;
    int h = lane >> 4;

    int cnt0 = cnt_src[n]; if (cnt0 > CAP) cnt0 = CAP;
    int cnt1 = cnt_trg[n]; if (cnt1 > CAP) cnt1 = CAP;

    // phase 1: transposed dense adjacency reads
    if (lane < cnt0){
        uint32_t nbr = nbrT[(size_t)lane*NN + n];
        uint2 e2     = evT [(size_t)lane*NN + n];
        sh_nbr[0][wave][lane] = (int)nbr;
        float4_ evv = { bf_lo(e2.x), bf_hi(e2.x), bf_lo(e2.y), bf_hi(e2.y) };
        *(float4_*)&sh_ev[0][wave][lane*4] = evv;
    }
    if (lane < cnt1){
        uint32_t nbr = nbrT[(size_t)(CAP + lane)*NN + n];
        uint2 e2     = evT [(size_t)(CAP + lane)*NN + n];
        sh_nbr[1][wave][lane] = (int)nbr;
        float4_ evv = { bf_lo(e2.x), bf_hi(e2.x), bf_lo(e2.y), bf_hi(e2.y) };
        *(float4_*)&sh_ev[1][wave][lane*4] = evv;
    }

    // skip + bias (issued before the barrier to overlap)
    uint32_t sv = ((const uint32_t*)(skip + (size_t)n * 128))[lane];
    float b0 = bias[2*lane], b1 = bias[2*lane + 1];

    __syncthreads();

    float sk0 = bf_lo(sv) + b0;
    float sk1 = bf_hi(sv) + b1;

    // phase 2a: src-direction aggregation (cols 0..127)
    float a0 = 0.f, a1 = 0.f, ad = 0.f;
    #pragma unroll 4
    for (int i = 0; i < cnt0; i++){
        int nbr  = sh_nbr[0][wave][i];
        float evw = sh_ev[0][wave][i*4 + h];
        uint32_t pv = ((const uint32_t*)(proj + (size_t)nbr * 128))[lane];
        a0 += evw * bf_lo(pv);
        a1 += evw * bf_hi(pv);
        ad += evw;
    }
    float inv = 1.f / (ad + 1e-16f);
    float f0 = a0 * inv + sk0;
    float f1 = a1 * inv + sk1;

    // phase 2b: trg-direction aggregation (cols 128..255)
    a0 = 0.f; a1 = 0.f; ad = 0.f;
    #pragma unroll 4
    for (int i = 0; i < cnt1; i++){
        int nbr  = sh_nbr[1][wave][i];
        float evw = sh_ev[1][wave][i*4 + h];
        uint32_t pv = ((const uint32_t*)(proj + (size_t)nbr * 128))[lane];
        a0 += evw * bf_lo(pv);
        a1 += evw * bf_hi(pv);
        ad += evw;
    }
    inv = 1.f / (ad + 1e-16f);
    float f2 = a0 * inv + sk0;
    float f3 = a1 * inv + sk1;

    // LayerNorm over 256 features
    float sum = f0 + f1 + f2 + f3;
    float sq  = f0*f0 + f1*f1 + f2*f2 + f3*f3;
    #pragma unroll
    for (int m = 1; m < 64; m <<= 1){
        sum += __shfl_xor(sum, m, 64);
        sq  += __shfl_xor(sq,  m, 64);
    }
    float mu  = sum * (1.f/256.f);
    float var = sq * (1.f/256.f) - mu*mu;
    var = var < 0.f ? 0.f : var;
    float rr = rsqrtf(var + 1e-5f);

    float o0 = (f0 - mu) * rr * gamma[2*lane]           + beta[2*lane];
    float o1 = (f1 - mu) * rr * gamma[2*lane + 1]       + beta[2*lane + 1];
    float o2 = (f2 - mu) * rr * gamma[128 + 2*lane]     + beta[128 + 2*lane];
    float o3 = (f3 - mu) * rr * gamma[128 + 2*lane + 1] + beta[128 + 2*lane + 1];

    float* orow = out + (size_t)n * 256;
    *(float2*)(orow + 2*lane)       = make_float2(o0, o1);
    *(float2*)(orow + 128 + 2*lane) = make_float2(o2, o3);
}

// ---------------------------------------------------------------------------
extern "C" void kernel_launch(void* const* d_in, const int* in_sizes, int n_in,
                              void* d_out, int out_size, void* d_ws, size_t ws_size,
                              hipStream_t stream)
{
    const float* x      = (const float*)d_in[0];
    const int*   eidx   = (const int*)d_in[1];
    const float* edges  = (const float*)d_in[2];
    const float* ins    = (const float*)d_in[3];
    const int*   bids   = (const int*)d_in[4];
    const float* Wproj  = (const float*)d_in[6];
    const float* Wedge  = (const float*)d_in[7];
    const float* Wsrc   = (const float*)d_in[8];
    const float* bsrc   = (const float*)d_in[9];
    const float* Wtrg   = (const float*)d_in[10];
    const float* btrg   = (const float*)d_in[11];
    const float* Wedgi  = (const float*)d_in[12];
    const float* bedgi  = (const float*)d_in[13];
    const float* a_src  = (const float*)d_in[14];
    const float* a_trg  = (const float*)d_in[15];
    const float* a_edge = (const float*)d_in[16];
    const float* bias   = (const float*)d_in[17];
    const float* Wskip  = (const float*)d_in[18];
    const float* gamma  = (const float*)d_in[19];
    const float* beta   = (const float*)d_in[20];

    char* ws = (char*)d_ws;
    size_t off = 0;
    ushortT* proj  = (ushortT*)(ws + off); off += (size_t)NN * 128 * 2;
    ushortT* skip  = (ushortT*)(ws + off); off += (size_t)NN * 128 * 2;
    ushortT* WcatT = (ushortT*)(ws + off); off += 256 * 128 * 2;
    float*   csrc  = (float*)(ws + off);   off += BB * HFD * 4;
    float*   ctrg  = (float*)(ws + off);   off += BB * HFD * 4;
    float*   M     = (float*)(ws + off);   off += BB * 256 * 4;
    float*   s_src = (float*)(ws + off);   off += (size_t)NN * 4 * 4;
    float*   s_trg = (float*)(ws + off);   off += (size_t)NN * 4 * 4;
    int*     cnt_src = (int*)(ws + off);   off += (size_t)NN * 4;
    int*     cnt_trg = (int*)(ws + off);   off += (size_t)NN * 4;
    int*     head_src = (int*)(ws + off);  off += (size_t)NN * 4;   // head_src+head_trg contiguous
    int*     head_trg = (int*)(ws + off);  off += (size_t)NN * 4;
    int*     next_src = (int*)(ws + off);  off += (size_t)EEc * 4;
    int*     next_trg = (int*)(ws + off);  off += (size_t)EEc * 4;
    uint4*   recs  = (uint4*)(ws + off);   off += (size_t)EEc * 16;
    uint32_t* nbrT = (uint32_t*)(ws + off); off += (size_t)2 * CAP * NN * 4;
    uint2*   evT   = (uint2*)(ws + off);   off += (size_t)2 * CAP * NN * 8;

    hipMemsetAsync(head_src, 0xFF, (size_t)NN * 4 * 2, stream);  // heads = -1

    k_bridge<<<dim3(BB), dim3(128), 0, stream>>>(ins, Wsrc, bsrc, Wtrg, btrg, Wedgi, bedgi,
                                                 a_src, a_trg, a_edge, Wedge, csrc, ctrg, M);
    k_transpose<<<dim3(128), dim3(256), 0, stream>>>(Wproj, Wskip, WcatT);
    k_gemm<<<dim3(NN/64), dim3(256), 0, stream>>>(x, WcatT, csrc, ctrg, proj, skip, s_src, s_trg);
    k_score<<<dim3(EEc/64), dim3(256), 0, stream>>>(eidx, bids, edges, M, s_src, s_trg,
                                                    recs, head_src, head_trg, next_src, next_trg);
    k_walk<<<dim3(2*NN/256), dim3(256), 0, stream>>>(head_src, head_trg, next_src, next_trg,
                                                     recs, cnt_src, cnt_trg, nbrT, evT);
    k_agg<<<dim3(NN/4), dim3(256), 0, stream>>>(proj, skip, bias, cnt_src, cnt_trg,
                                                nbrT, evT, gamma, beta, (float*)d_out);
}

// Round 7
// 539.775 us; speedup vs baseline: 1.0901x; 1.0011x over previous
//
#include <hip/hip_runtime.h>
#include <stdint.h>

typedef unsigned short ushortT;
typedef __attribute__((ext_vector_type(8))) short short8;
typedef __attribute__((ext_vector_type(4))) float float4_;

#define HH 4
#define FF 32
#define HFD 128
#define F_IN 128
#define EDGE_DIM 64
#define HIDDEN 256
#define BB 64
#define MLE 1500
#define NN 96000
#define EEc 600000
#define CAP 32

__device__ __forceinline__ float bf_lo(uint32_t u){ return __uint_as_float(u << 16); }
__device__ __forceinline__ float bf_hi(uint32_t u){ return __uint_as_float(u & 0xffff0000u); }
__device__ __forceinline__ uint32_t f2bf(float f){
    uint32_t u = __float_as_uint(f);
    return (u + 0x7fffu + ((u >> 16) & 1u)) >> 16;
}
__device__ __forceinline__ short8 cvt8(const float* p){
    float4_ x0 = *(const float4_*)p;
    float4_ x1 = *(const float4_*)(p + 4);
    short8 r;
    r[0]=(short)f2bf(x0[0]); r[1]=(short)f2bf(x0[1]); r[2]=(short)f2bf(x0[2]); r[3]=(short)f2bf(x0[3]);
    r[4]=(short)f2bf(x1[0]); r[5]=(short)f2bf(x1[1]); r[6]=(short)f2bf(x1[2]); r[7]=(short)f2bf(x1[3]);
    return r;
}

// ---------------------------------------------------------------------------
// K1: bridges (fp32).  csrc[b,hf]=(ins@Wsrc+bsrc)*a_src ; ctrg likewise.
//     cedge in LDS, then M2[b][h][d] = sum_f W_edge[d,h*32+f] * cedge[b,h*32+f]
//     M layout [b][h][d] so k_score group-loads contiguous 256B runs.
// grid: 64 blocks x 128 threads
// ---------------------------------------------------------------------------
__global__ void k_bridge(const float* ins, const float* Wsrc, const float* bsrc,
                         const float* Wtrg, const float* btrg,
                         const float* Wedg, const float* bedg,
                         const float* a_src, const float* a_trg, const float* a_edge,
                         const float* W_edge,
                         float* csrc, float* ctrg, float* Mout)
{
    __shared__ float ins_s[HIDDEN];
    __shared__ float ce_s[HFD];
    int b = blockIdx.x, t = threadIdx.x;  // t in [0,128)
    const float* ip = ins + b * HIDDEN;
    ins_s[t]       = ip[t];
    ins_s[t + 128] = ip[t + 128];
    __syncthreads();
    float as = 0.f, at = 0.f, ae = 0.f;
    #pragma unroll 8
    for (int k = 0; k < HIDDEN; k++){
        float iv = ins_s[k];
        as += iv * Wsrc[k*HFD + t];
        at += iv * Wtrg[k*HFD + t];
        ae += iv * Wedg[k*HFD + t];
    }
    csrc[b*HFD + t] = (as + bsrc[t]) * a_src[t];
    ctrg[b*HFD + t] = (at + btrg[t]) * a_trg[t];
    ce_s[t] = (ae + bedg[t]) * a_edge[t];
    __syncthreads();
    #pragma unroll
    for (int rep = 0; rep < 2; rep++){
        int idx = t + rep * 128;      // 0..255
        int d = idx >> 2, h = idx & 3;
        float acc = 0.f;
        #pragma unroll
        for (int f = 0; f < FF; f++)
            acc += W_edge[d*HFD + h*FF + f] * ce_s[h*FF + f];
        Mout[b*256 + h*64 + d] = acc;       // transposed: [b][h][d]
    }
}

// ---------------------------------------------------------------------------
// K_t: WcatT[c][d] = bf16( c<128 ? W_proj[d][c] : W_skip[d][c-128] )
// grid: 128 blocks x 256 threads
// ---------------------------------------------------------------------------
__global__ void k_transpose(const float* Wp, const float* Wsk, ushortT* WcatT)
{
    int idx = blockIdx.x * 256 + threadIdx.x;
    int c = idx >> 7;          // 0..255
    int d = idx & 127;         // 0..127
    float v = (c < 128) ? Wp[d*128 + c] : Wsk[d*128 + (c - 128)];
    WcatT[c*128 + d] = (ushortT)f2bf(v);
}

// ---------------------------------------------------------------------------
// K2: GEMM + fused scores (unchanged).
// grid: 1500 blocks x 256 threads
// ---------------------------------------------------------------------------
__global__ __launch_bounds__(256) void k_gemm(const float* x, const ushortT* WcatT,
                                              const float* csrc, const float* ctrg,
                                              ushortT* proj, ushortT* skip,
                                              float* s_src, float* s_trg)
{
    int t = threadIdx.x;
    int w = t >> 6, lane = t & 63;
    int q = lane >> 4, n16 = lane & 15;
    size_t node = (size_t)blockIdx.x * 64 + w * 16 + n16;

    float4_ acc[16];
    #pragma unroll
    for (int j = 0; j < 16; j++) acc[j] = (float4_){0.f, 0.f, 0.f, 0.f};

    #pragma unroll
    for (int kk = 0; kk < 4; kk++){
        short8 bfrag = cvt8(x + node * 128 + kk*32 + q*8);   // B[k][n=node]
        #pragma unroll
        for (int j = 0; j < 16; j++){
            short8 afrag = *(const short8*)(WcatT + (size_t)(j*16 + n16) * 128 + kk*32 + q*8);
            acc[j] = __builtin_amdgcn_mfma_f32_16x16x32_bf16(afrag, bfrag, acc[j], 0, 0, 0);
        }
    }

    // ---- store proj (j<8) / skip (j>=8): 8B packed per j ----
    #pragma unroll
    for (int j = 0; j < 16; j++){
        uint32_t p0 = f2bf(acc[j][0]) | (f2bf(acc[j][1]) << 16);
        uint32_t p1 = f2bf(acc[j][2]) | (f2bf(acc[j][3]) << 16);
        ushortT* base = (j < 8) ? (proj + node*128 + j*16 + q*4)
                                : (skip + node*128 + (j-8)*16 + q*4);
        uint2 pv; pv.x = p0; pv.y = p1;
        *(uint2*)base = pv;
    }

    // ---- fused scores: s[n,h] = sum_f proj_f32[n,h*32+f] * c[b,h*32+f] ----
    int b = (int)(node / MLE);
    const float* cs = csrc + b * HFD;
    const float* ct = ctrg + b * HFD;
    float ps[4] = {0,0,0,0}, pt[4] = {0,0,0,0};
    #pragma unroll
    for (int j = 0; j < 8; j++){
        int h = j >> 1;
        #pragma unroll
        for (int r = 0; r < 4; r++){
            int c = j*16 + q*4 + r;
            ps[h] += acc[j][r] * cs[c];
            pt[h] += acc[j][r] * ct[c];
        }
    }
    #pragma unroll
    for (int m = 16; m < 64; m <<= 1){
        #pragma unroll
        for (int hh = 0; hh < 4; hh++){
            ps[hh] += __shfl_xor(ps[hh], m, 64);
            pt[hh] += __shfl_xor(pt[hh], m, 64);
        }
    }
    float vs = (q == 0) ? ps[0] : (q == 1) ? ps[1] : (q == 2) ? ps[2] : ps[3];
    float vt = (q == 0) ? pt[0] : (q == 1) ? pt[1] : (q == 2) ? pt[2] : pt[3];
    s_src[node*4 + q] = vs;
    s_trg[node*4 + q] = vt;
}

// ---------------------------------------------------------------------------
// K4 (k_score): streaming per-edge scores + exp -> coalesced REC stream +
//   linked-list adjacency build (atomicExch head, coalesced next).
//   THIS ROUND: deep-MLP restructure.  All loads issued up front in latency
//   order (edges HBM -> bids -> eidx -> M[16] into regs -> s gathers), then
//   a pure-FMA dot block with no interleaved waits.  ~24 outstanding loads
//   per wave (was ~8) at ~4 waves/SIMD.  Epilogue atomics split across
//   h_sel==0 (src list) and h_sel==1 (trg list) lanes.
// grid: E/64 blocks x 256 threads (64 edges per block, 16 per wave)
// ---------------------------------------------------------------------------
__global__ __launch_bounds__(256) void k_score(const int* eidx, const int* bids,
    const float* edges, const float* M, const float* s_src, const float* s_trg,
    uint4* recs, int* head_src, int* head_trg, int* next_src, int* next_trg)
{
    int t = threadIdx.x;
    int wave = t >> 6, l = t & 63;
    int g = l >> 4, s = l & 15;
    int eb = (blockIdx.x * 4 + wave) * 16;   // first edge of this wave's tile

    // ---- (1) HBM edge-row loads first: lane holds floats d=s*4..3 of row i*4+g
    float4_ ev[4];
    #pragma unroll
    for (int i = 0; i < 4; i++)
        ev[i] = *(const float4_*)(edges + (size_t)(eb + i*4 + g) * 64 + s*4);

    // ---- (2) bids
    int bidv[4];
    #pragma unroll
    for (int i = 0; i < 4; i++)
        bidv[i] = bids[eb + i*4 + g];

    // ---- (3) eidx for this lane's epilogue edge
    int i_sel = s >> 2;
    int h_sel = s & 3;
    int e   = eb + i_sel*4 + g;
    int src = eidx[e];
    int trg = eidx[EEc + e];

    // ---- (4) ALL 16 M float4s into registers (static indices, no scratch)
    float4_ mr[16];
    #pragma unroll
    for (int i = 0; i < 4; i++){
        const float* Mb = M + (size_t)bidv[i] * 256;
        mr[i*4+0] = *(const float4_*)(Mb +   0 + s*4);
        mr[i*4+1] = *(const float4_*)(Mb +  64 + s*4);
        mr[i*4+2] = *(const float4_*)(Mb + 128 + s*4);
        mr[i*4+3] = *(const float4_*)(Mb + 192 + s*4);
    }

    // ---- (5) s-gathers (depend only on eidx)
    float ssv = s_src[(size_t)src*4 + h_sel];
    float stv = s_trg[(size_t)trg*4 + h_sel];

    // ---- (6) pure-FMA dot block: p[i][h] partials
    float p00,p01,p02,p03, p10,p11,p12,p13, p20,p21,p22,p23, p30,p31,p32,p33;
    {
        float4_ e4;
        e4 = ev[0];
        p00 = e4[0]*mr[0][0] + e4[1]*mr[0][1] + e4[2]*mr[0][2] + e4[3]*mr[0][3];
        p01 = e4[0]*mr[1][0] + e4[1]*mr[1][1] + e4[2]*mr[1][2] + e4[3]*mr[1][3];
        p02 = e4[0]*mr[2][0] + e4[1]*mr[2][1] + e4[2]*mr[2][2] + e4[3]*mr[2][3];
        p03 = e4[0]*mr[3][0] + e4[1]*mr[3][1] + e4[2]*mr[3][2] + e4[3]*mr[3][3];
        e4 = ev[1];
        p10 = e4[0]*mr[4][0] + e4[1]*mr[4][1] + e4[2]*mr[4][2] + e4[3]*mr[4][3];
        p11 = e4[0]*mr[5][0] + e4[1]*mr[5][1] + e4[2]*mr[5][2] + e4[3]*mr[5][3];
        p12 = e4[0]*mr[6][0] + e4[1]*mr[6][1] + e4[2]*mr[6][2] + e4[3]*mr[6][3];
        p13 = e4[0]*mr[7][0] + e4[1]*mr[7][1] + e4[2]*mr[7][2] + e4[3]*mr[7][3];
        e4 = ev[2];
        p20 = e4[0]*mr[8][0] + e4[1]*mr[8][1] + e4[2]*mr[8][2] + e4[3]*mr[8][3];
        p21 = e4[0]*mr[9][0] + e4[1]*mr[9][1] + e4[2]*mr[9][2] + e4[3]*mr[9][3];
        p22 = e4[0]*mr[10][0] + e4[1]*mr[10][1] + e4[2]*mr[10][2] + e4[3]*mr[10][3];
        p23 = e4[0]*mr[11][0] + e4[1]*mr[11][1] + e4[2]*mr[11][2] + e4[3]*mr[11][3];
        e4 = ev[3];
        p30 = e4[0]*mr[12][0] + e4[1]*mr[12][1] + e4[2]*mr[12][2] + e4[3]*mr[12][3];
        p31 = e4[0]*mr[13][0] + e4[1]*mr[13][1] + e4[2]*mr[13][2] + e4[3]*mr[13][3];
        p32 = e4[0]*mr[14][0] + e4[1]*mr[14][1] + e4[2]*mr[14][2] + e4[3]*mr[14][3];
        p33 = e4[0]*mr[15][0] + e4[1]*mr[15][1] + e4[2]*mr[15][2] + e4[3]*mr[15][3];
    }

    // ---- reduce over the 16-lane group (xor 1,2,4,8 stays within group)
    #pragma unroll
    for (int mm = 1; mm < 16; mm <<= 1){
        p00 += __shfl_xor(p00, mm, 64); p01 += __shfl_xor(p01, mm, 64);
        p02 += __shfl_xor(p02, mm, 64); p03 += __shfl_xor(p03, mm, 64);
        p10 += __shfl_xor(p10, mm, 64); p11 += __shfl_xor(p11, mm, 64);
        p12 += __shfl_xor(p12, mm, 64); p13 += __shfl_xor(p13, mm, 64);
        p20 += __shfl_xor(p20, mm, 64); p21 += __shfl_xor(p21, mm, 64);
        p22 += __shfl_xor(p22, mm, 64); p23 += __shfl_xor(p23, mm, 64);
        p30 += __shfl_xor(p30, mm, 64); p31 += __shfl_xor(p31, mm, 64);
        p32 += __shfl_xor(p32, mm, 64); p33 += __shfl_xor(p33, mm, 64);
    }

    // ---- epilogue: lane (g, s) handles edge eb + (s>>2)*4 + g, head s&3
    float q0 = h_sel==0 ? p00 : h_sel==1 ? p01 : h_sel==2 ? p02 : p03;
    float q1 = h_sel==0 ? p10 : h_sel==1 ? p11 : h_sel==2 ? p12 : p13;
    float q2 = h_sel==0 ? p20 : h_sel==1 ? p21 : h_sel==2 ? p22 : p23;
    float q3 = h_sel==0 ? p30 : h_sel==1 ? p31 : h_sel==2 ? p32 : p33;
    float se = i_sel==0 ? q0 : i_sel==1 ? q1 : i_sel==2 ? q2 : q3;

    float sc = ssv + stv + se;
    sc = sc > 0.f ? sc : 0.2f * sc;
    float exv = __expf(sc);

    // pack the cluster's 4 head values as bf16x4 into lane h_sel==0
    uint32_t my   = f2bf(exv) << ((h_sel & 1) * 16);
    uint32_t pair = my | __shfl_xor(my, 1, 64);       // h0: ex0|ex1  h2: ex2|ex3
    uint32_t both = __shfl_xor(pair, 2, 64);          // h0: ex2|ex3

    // split epilogue: h_sel==0 -> rec + src list; h_sel==1 -> trg list
    if (h_sel == 0){
        uint4 rec;
        rec.x = (uint32_t)src; rec.y = (uint32_t)trg;
        rec.z = pair; rec.w = both;
        recs[e] = rec;                                 // coalesced 16B stream
        int old0 = atomicExch(&head_src[src], e);
        next_src[e] = old0;                            // coalesced 4B
    } else if (h_sel == 1){
        int old1 = atomicExch(&head_trg[trg], e);
        next_trg[e] = old1;                            // coalesced 4B
    }
}

// ---------------------------------------------------------------------------
// K4b (k_walk): linked lists -> transposed dense adjacency.
//   One node-direction per lane (192000 lanes = 750 blocks; all waves
//   co-resident -> the ~6-hop dependent-load chain is fully latency-hidden).
//   At hop c, all active lanes store at [c][n] with consecutive n: COALESCED.
//   Entry content (nbr + ex4) inlined from recs so k_agg needs no rec gather.
// grid: 750 blocks x 256 threads
// ---------------------------------------------------------------------------
__global__ __launch_bounds__(256) void k_walk(const int* head_src, const int* head_trg,
    const int* next_src, const int* next_trg, const uint4* recs,
    int* cnt_src, int* cnt_trg, uint32_t* nbrT, uint2* evT)   // [2][CAP][NN]
{
    int id = blockIdx.x * 256 + threadIdx.x;   // 0..191999, dir block-uniform
    int dir = (id >= NN) ? 1 : 0;
    int n = id - dir * NN;
    int e = dir ? head_trg[n] : head_src[n];
    const int* nx = dir ? next_trg : next_src;
    uint32_t* nT = nbrT + (size_t)dir * CAP * NN;
    uint2*    eT = evT  + (size_t)dir * CAP * NN;
    int c = 0;
    while (e >= 0 && c < CAP){
        uint4 r = recs[e];           // scattered 16B (L2/IC-hot, 9.6MB)
        int en = nx[e];              // independent of recs load
        nT[(size_t)c*NN + n] = dir ? r.x : r.y;
        eT[(size_t)c*NN + n] = make_uint2(r.z, r.w);
        e = en;
        c++;
    }
    if (dir) cnt_trg[n] = c; else cnt_src[n] = c;
}

// ---------------------------------------------------------------------------
// K5: fused aggregation + softmax + skip + bias + LayerNorm.
//     Phase 1 reads the transposed dense adjacency: nbrT/evT[l][n] lines are
//     shared by the block's 4 consecutive nodes (was: 2 random gathers/edge).
// grid: 24000 blocks x 256 threads (one wave per node)
// ---------------------------------------------------------------------------
__global__ __launch_bounds__(256) void k_agg(const ushortT* proj, const ushortT* skip,
    const float* bias,
    const int* cnt_src, const int* cnt_trg,
    const uint32_t* nbrT, const uint2* evT,
    const float* gamma, const float* beta, float* out)
{
    __shared__ int   sh_nbr[2][4][CAP];
    __shared__ float sh_ev [2][4][CAP*4];

    int wave = threadIdx.x >> 6, lane = threadIdx.x & 63;
    int n = blockIdx.x * 4 + wave;
    int h = lane >> 4;

    int cnt0 = cnt_src[n]; if (cnt0 > CAP) cnt0 = CAP;
    int cnt1 = cnt_trg[n]; if (cnt1 > CAP) cnt1 = CAP;

    // phase 1: transposed dense adjacency reads
    if (lane < cnt0){
        uint32_t nbr = nbrT[(size_t)lane*NN + n];
        uint2 e2     = evT [(size_t)lane*NN + n];
        sh_nbr[0][wave][lane] = (int)nbr;
        float4_ evv = { bf_lo(e2.x), bf_hi(e2.x), bf_lo(e2.y), bf_hi(e2.y) };
        *(float4_*)&sh_ev[0][wave][lane*4] = evv;
    }
    if (lane < cnt1){
        uint32_t nbr = nbrT[(size_t)(CAP + lane)*NN + n];
        uint2 e2     = evT [(size_t)(CAP + lane)*NN + n];
        sh_nbr[1][wave][lane] = (int)nbr;
        float4_ evv = { bf_lo(e2.x), bf_hi(e2.x), bf_lo(e2.y), bf_hi(e2.y) };
        *(float4_*)&sh_ev[1][wave][lane*4] = evv;
    }

    // skip + bias (issued before the barrier to overlap)
    uint32_t sv = ((const uint32_t*)(skip + (size_t)n * 128))[lane];
    float b0 = bias[2*lane], b1 = bias[2*lane + 1];

    __syncthreads();

    float sk0 = bf_lo(sv) + b0;
    float sk1 = bf_hi(sv) + b1;

    // phase 2a: src-direction aggregation (cols 0..127)
    float a0 = 0.f, a1 = 0.f, ad = 0.f;
    #pragma unroll 4
    for (int i = 0; i < cnt0; i++){
        int nbr  = sh_nbr[0][wave][i];
        float evw = sh_ev[0][wave][i*4 + h];
        uint32_t pv = ((const uint32_t*)(proj + (size_t)nbr * 128))[lane];
        a0 += evw * bf_lo(pv);
        a1 += evw * bf_hi(pv);
        ad += evw;
    }
    float inv = 1.f / (ad + 1e-16f);
    float f0 = a0 * inv + sk0;
    float f1 = a1 * inv + sk1;

    // phase 2b: trg-direction aggregation (cols 128..255)
    a0 = 0.f; a1 = 0.f; ad = 0.f;
    #pragma unroll 4
    for (int i = 0; i < cnt1; i++){
        int nbr  = sh_nbr[1][wave][i];
        float evw = sh_ev[1][wave][i*4 + h];
        uint32_t pv = ((const uint32_t*)(proj + (size_t)nbr * 128))[lane];
        a0 += evw * bf_lo(pv);
        a1 += evw * bf_hi(pv);
        ad += evw;
    }
    inv = 1.f / (ad + 1e-16f);
    float f2 = a0 * inv + sk0;
    float f3 = a1 * inv + sk1;

    // LayerNorm over 256 features
    float sum = f0 + f1 + f2 + f3;
    float sq  = f0*f0 + f1*f1 + f2*f2 + f3*f3;
    #pragma unroll
    for (int m = 1; m < 64; m <<= 1){
        sum += __shfl_xor(sum, m, 64);
        sq  += __shfl_xor(sq,  m, 64);
    }
    float mu  = sum * (1.f/256.f);
    float var = sq * (1.f/256.f) - mu*mu;
    var = var < 0.f ? 0.f : var;
    float rr = rsqrtf(var + 1e-5f);

    float o0 = (f0 - mu) * rr * gamma[2*lane]           + beta[2*lane];
    float o1 = (f1 - mu) * rr * gamma[2*lane + 1]       + beta[2*lane + 1];
    float o2 = (f2 - mu) * rr * gamma[128 + 2*lane]     + beta[128 + 2*lane];
    float o3 = (f3 - mu) * rr * gamma[128 + 2*lane + 1] + beta[128 + 2*lane + 1];

    float* orow = out + (size_t)n * 256;
    *(float2*)(orow + 2*lane)       = make_float2(o0, o1);
    *(float2*)(orow + 128 + 2*lane) = make_float2(o2, o3);
}

// ---------------------------------------------------------------------------
extern "C" void kernel_launch(void* const* d_in, const int* in_sizes, int n_in,
                              void* d_out, int out_size, void* d_ws, size_t ws_size,
                              hipStream_t stream)
{
    const float* x      = (const float*)d_in[0];
    const int*   eidx   = (const int*)d_in[1];
    const float* edges  = (const float*)d_in[2];
    const float* ins    = (const float*)d_in[3];
    const int*   bids   = (const int*)d_in[4];
    const float* Wproj  = (const float*)d_in[6];
    const float* Wedge  = (const float*)d_in[7];
    const float* Wsrc   = (const float*)d_in[8];
    const float* bsrc   = (const float*)d_in[9];
    const float* Wtrg   = (const float*)d_in[10];
    const float* btrg   = (const float*)d_in[11];
    const float* Wedgi  = (const float*)d_in[12];
    const float* bedgi  = (const float*)d_in[13];
    const float* a_src  = (const float*)d_in[14];
    const float* a_trg  = (const float*)d_in[15];
    const float* a_edge = (const float*)d_in[16];
    const float* bias   = (const float*)d_in[17];
    const float* Wskip  = (const float*)d_in[18];
    const float* gamma  = (const float*)d_in[19];
    const float* beta   = (const float*)d_in[20];

    char* ws = (char*)d_ws;
    size_t off = 0;
    ushortT* proj  = (ushortT*)(ws + off); off += (size_t)NN * 128 * 2;
    ushortT* skip  = (ushortT*)(ws + off); off += (size_t)NN * 128 * 2;
    ushortT* WcatT = (ushortT*)(ws + off); off += 256 * 128 * 2;
    float*   csrc  = (float*)(ws + off);   off += BB * HFD * 4;
    float*   ctrg  = (float*)(ws + off);   off += BB * HFD * 4;
    float*   M     = (float*)(ws + off);   off += BB * 256 * 4;
    float*   s_src = (float*)(ws + off);   off += (size_t)NN * 4 * 4;
    float*   s_trg = (float*)(ws + off);   off += (size_t)NN * 4 * 4;
    int*     cnt_src = (int*)(ws + off);   off += (size_t)NN * 4;
    int*     cnt_trg = (int*)(ws + off);   off += (size_t)NN * 4;
    int*     head_src = (int*)(ws + off);  off += (size_t)NN * 4;   // head_src+head_trg contiguous
    int*     head_trg = (int*)(ws + off);  off += (size_t)NN * 4;
    int*     next_src = (int*)(ws + off);  off += (size_t)EEc * 4;
    int*     next_trg = (int*)(ws + off);  off += (size_t)EEc * 4;
    uint4*   recs  = (uint4*)(ws + off);   off += (size_t)EEc * 16;
    uint32_t* nbrT = (uint32_t*)(ws + off); off += (size_t)2 * CAP * NN * 4;
    uint2*   evT   = (uint2*)(ws + off);   off += (size_t)2 * CAP * NN * 8;

    hipMemsetAsync(head_src, 0xFF, (size_t)NN * 4 * 2, stream);  // heads = -1

    k_bridge<<<dim3(BB), dim3(128), 0, stream>>>(ins, Wsrc, bsrc, Wtrg, btrg, Wedgi, bedgi,
                                                 a_src, a_trg, a_edge, Wedge, csrc, ctrg, M);
    k_transpose<<<dim3(128), dim3(256), 0, stream>>>(Wproj, Wskip, WcatT);
    k_gemm<<<dim3(NN/64), dim3(256), 0, stream>>>(x, WcatT, csrc, ctrg, proj, skip, s_src, s_trg);
    k_score<<<dim3(EEc/64), dim3(256), 0, stream>>>(eidx, bids, edges, M, s_src, s_trg,
                                                    recs, head_src, head_trg, next_src, next_trg);
    k_walk<<<dim3(2*NN/256), dim3(256), 0, stream>>>(head_src, head_trg, next_src, next_trg,
                                                     recs, cnt_src, cnt_trg, nbrT, evT);
    k_agg<<<dim3(NN/4), dim3(256), 0, stream>>>(proj, skip, bias, cnt_src, cnt_trg,
                                                nbrT, evT, gamma, beta, (float*)d_out);
}